// Round 15
// baseline (380.778 us; speedup 1.0000x reference)
//
#include <hip/hip_runtime.h>
#include <math.h>

#define NODES  50000
#define EDGES  800000
#define GRAPHS 256
#define FEAT   128
#define STATE  64
#define M_OUT  32
#define ROUNDS 4
#define NT32   ((NODES + 31) / 32)     // 1563 tiles of 32 nodes
#define HALF   32                      // features per plane
#define PLANE  (50000L * 32L)          // bf16 elements per plane (3.2 MB)
#define SCAN_BLOCKS ((NODES + 1023) / 1024)  // 49

typedef unsigned short bfraw;

__device__ __forceinline__ float bf2f(bfraw u) {
    union { unsigned int i; float f; } v; v.i = ((unsigned int)u) << 16; return v.f;
}
__device__ __forceinline__ bfraw f2bf(float f) {
    union { float f; unsigned int i; } v; v.f = f;
    unsigned int r = v.i + 0x7FFF + ((v.i >> 16) & 1); // round-nearest-even
    return (bfraw)(r >> 16);
}
__device__ __forceinline__ int packbf(float lo, float hi) {
    return ((int)f2bf(hi) << 16) | (int)f2bf(lo);
}
__device__ __forceinline__ void addv8(float* acc, int4 v, float m) {
    union { int i; float f; } t;
    t.i = v.x << 16;                  acc[0] += t.f * m;
    t.i = v.x & (int)0xffff0000;      acc[1] += t.f * m;
    t.i = v.y << 16;                  acc[2] += t.f * m;
    t.i = v.y & (int)0xffff0000;      acc[3] += t.f * m;
    t.i = v.z << 16;                  acc[4] += t.f * m;
    t.i = v.z & (int)0xffff0000;      acc[5] += t.f * m;
    t.i = v.w << 16;                  acc[6] += t.f * m;
    t.i = v.w & (int)0xffff0000;      acc[7] += t.f * m;
}
__device__ __forceinline__ void unpack8(float* d, int4 v) {
    union { int i; float f; } t;
    t.i = v.x << 16;              d[0] = t.f;
    t.i = v.x & (int)0xffff0000;  d[1] = t.f;
    t.i = v.y << 16;              d[2] = t.f;
    t.i = v.y & (int)0xffff0000;  d[3] = t.f;
    t.i = v.z << 16;              d[4] = t.f;
    t.i = v.z & (int)0xffff0000;  d[5] = t.f;
    t.i = v.w << 16;              d[6] = t.f;
    t.i = v.w & (int)0xffff0000;  d[7] = t.f;
}
__device__ __forceinline__ int4 pack8(const float* a) {
    int4 o;
    o.x = packbf(a[0], a[1]); o.y = packbf(a[2], a[3]);
    o.z = packbf(a[4], a[5]); o.w = packbf(a[6], a[7]);
    return o;
}

// ---------------------------------------------------------------------------
// Merged full-row gather: 8 lanes/node (lanes 0-3 plane0, 4-7 plane1),
// 32 nodes/block, 16B loads, 4 edges in flight (4-deep: tail waste 20%->11%,
// ILP beyond 4 measured near-worthless). uint16 csr, bf16 agg output.
// ---------------------------------------------------------------------------
__global__ __launch_bounds__(256) void k_gather(
    const int* __restrict__ rowptr, const unsigned short* __restrict__ csr,
    const bfraw* __restrict__ plane0, const bfraw* __restrict__ plane1,
    bfraw* __restrict__ aggH0, bfraw* __restrict__ aggH1)
{
    // pre-warm: stream a sequential slice of each plane into cache
    float dummy = 0.f;
    {
        const bfraw* p = (threadIdx.x < 128) ? plane0 : plane1;
        long s = (long)blockIdx.x * 1024 + (long)(threadIdx.x & 127) * 8;
        if (s + 8 <= PLANE) {
            int4 a = *(const int4*)(p + s);
            union { int i; float f; } t; t.i = a.x << 16;
            dummy = t.f;   // finite; folded below with *0.0f
        }
    }

    int n = blockIdx.x * 32 + (threadIdx.x >> 3);
    if (n >= NODES) return;
    const int q = (threadIdx.x & 7) * 8;            // 0..56
    const bfraw* plane = (q < HALF) ? plane0 : plane1;
    const int qq = (q < HALF) ? q : q - HALF;       // offset within plane row
    int beg = rowptr[n], end = rowptr[n + 1];

    float acc[8] = {0.f, 0.f, 0.f, 0.f, 0.f, 0.f, 0.f, 0.f};
    for (int i = beg; i < end; i += 4) {
        int last = end - 1;
        int i1 = i + 1 < last ? i + 1 : last;
        int i2 = i + 2 < last ? i + 2 : last;
        int i3 = i + 3 < last ? i + 3 : last;
        int s0 = csr[i], s1 = csr[i1], s2 = csr[i2], s3 = csr[i3];
        int4 v0 = *(const int4*)(plane + (long)s0 * HALF + qq);
        int4 v1 = *(const int4*)(plane + (long)s1 * HALF + qq);
        int4 v2 = *(const int4*)(plane + (long)s2 * HALF + qq);
        int4 v3 = *(const int4*)(plane + (long)s3 * HALF + qq);
        float m1 = (i + 1 < end) ? 1.f : 0.f;
        float m2 = (i + 2 < end) ? 1.f : 0.f;
        float m3 = (i + 3 < end) ? 1.f : 0.f;
        addv8(acc, v0, 1.f); addv8(acc, v1, m1);
        addv8(acc, v2, m2);  addv8(acc, v3, m3);
    }
    acc[0] += dummy * 0.0f;

    bfraw* aout = (q < HALF) ? (aggH0 + (long)n * HALF + qq) : (aggH1 + (long)n * HALF + qq);
    *(int4*)aout = pack8(acc);
}

// ---------------------------------------------------------------------------
// state = relu(x @ inW + inb); msg planes = relu(state @ msgW + msgb).
// 32 nodes/block, 8 thr/node x 8 feats; one reused 16KB weight buffer.
// ---------------------------------------------------------------------------
__global__ __launch_bounds__(256) void k_in_msg(
    const float* __restrict__ x, const float* __restrict__ inW, const float* __restrict__ inb,
    const float* __restrict__ msgW, const float* __restrict__ msgb,
    float* __restrict__ state, bfraw* __restrict__ msg0, bfraw* __restrict__ msg1)
{
    __shared__ float sW[64 * STATE];        // 16 KB, reused 3x
    __shared__ float sInb[STATE], sMsgb[STATE];
    __shared__ float sx[32 * 132];          // 16.9 KB
    __shared__ float ss[32 * 68];           // 8.7 KB

    const int row = threadIdx.x >> 3;           // node in tile
    const int q8  = (threadIdx.x & 7) << 3;     // feature offset (8 wide)
    const int base = blockIdx.x * 32;
    const int n = base + row;

    if (threadIdx.x < STATE) {
        sInb[threadIdx.x]  = inb[threadIdx.x];
        sMsgb[threadIdx.x] = msgb[threadIdx.x];
    }
    for (int i = threadIdx.x; i < 1024; i += 256) {
        int r = i >> 5, q = (i & 31) << 2;
        float4 v = make_float4(0.f, 0.f, 0.f, 0.f);
        if (base + r < NODES) v = *(const float4*)(x + (long)(base + r) * FEAT + q);
        *(float4*)(sx + r * 132 + q) = v;
    }
    for (int i = threadIdx.x; i < 1024; i += 256)
        *(float4*)(sW + i * 4) = *(const float4*)(inW + i * 4);
    __syncthreads();

    float a[8];
    #pragma unroll
    for (int j = 0; j < 8; j++) a[j] = sInb[q8 + j];
    const float* xr = sx + row * 132;
    #pragma unroll 8
    for (int k = 0; k < 64; k++) {
        float xv = xr[k];
        float4 w0 = *(const float4*)(sW + k * STATE + q8);
        float4 w1 = *(const float4*)(sW + k * STATE + q8 + 4);
        a[0] += xv * w0.x; a[1] += xv * w0.y; a[2] += xv * w0.z; a[3] += xv * w0.w;
        a[4] += xv * w1.x; a[5] += xv * w1.y; a[6] += xv * w1.z; a[7] += xv * w1.w;
    }
    __syncthreads();
    for (int i = threadIdx.x; i < 1024; i += 256)
        *(float4*)(sW + i * 4) = *(const float4*)(inW + 64 * STATE + i * 4);
    __syncthreads();
    #pragma unroll 8
    for (int k = 0; k < 64; k++) {
        float xv = xr[64 + k];
        float4 w0 = *(const float4*)(sW + k * STATE + q8);
        float4 w1 = *(const float4*)(sW + k * STATE + q8 + 4);
        a[0] += xv * w0.x; a[1] += xv * w0.y; a[2] += xv * w0.z; a[3] += xv * w0.w;
        a[4] += xv * w1.x; a[5] += xv * w1.y; a[6] += xv * w1.z; a[7] += xv * w1.w;
    }
    #pragma unroll
    for (int j = 0; j < 8; j++) a[j] = fmaxf(a[j], 0.f);
    if (n < NODES) {
        *(float4*)(state + (long)n * STATE + q8)     = make_float4(a[0], a[1], a[2], a[3]);
        *(float4*)(state + (long)n * STATE + q8 + 4) = make_float4(a[4], a[5], a[6], a[7]);
    }
    *(float4*)(ss + row * 68 + q8)     = make_float4(a[0], a[1], a[2], a[3]);
    *(float4*)(ss + row * 68 + q8 + 4) = make_float4(a[4], a[5], a[6], a[7]);
    __syncthreads();
    for (int i = threadIdx.x; i < 1024; i += 256)
        *(float4*)(sW + i * 4) = *(const float4*)(msgW + i * 4);
    __syncthreads();

    float m[8];
    #pragma unroll
    for (int j = 0; j < 8; j++) m[j] = sMsgb[q8 + j];
    const float* sr = ss + row * 68;
    #pragma unroll 8
    for (int k = 0; k < STATE; k++) {
        float sv = sr[k];
        float4 w0 = *(const float4*)(sW + k * STATE + q8);
        float4 w1 = *(const float4*)(sW + k * STATE + q8 + 4);
        m[0] += sv * w0.x; m[1] += sv * w0.y; m[2] += sv * w0.z; m[3] += sv * w0.w;
        m[4] += sv * w1.x; m[5] += sv * w1.y; m[6] += sv * w1.z; m[7] += sv * w1.w;
    }
    #pragma unroll
    for (int j = 0; j < 8; j++) m[j] = fmaxf(m[j], 0.f);
    if (n < NODES) {
        bfraw* dst = (q8 < HALF) ? (msg0 + (long)n * HALF + q8) : (msg1 + (long)n * HALF + (q8 - HALF));
        *(int4*)dst = pack8(m);
    }
}

// ---------------------------------------------------------------------------
// CSR build: histogram + hierarchical scan + fill (u16 csr, NT edge streams)
// ---------------------------------------------------------------------------
__global__ __launch_bounds__(256) void k_hist(const int* __restrict__ ei, int* __restrict__ deg)
{
    int e = blockIdx.x * 256 + threadIdx.x;
    if (e < EDGES) atomicAdd(&deg[__builtin_nontemporal_load(ei + EDGES + e)], 1);
}

__global__ __launch_bounds__(1024) void k_scan1(const int* __restrict__ deg,
                                                int* __restrict__ part, int* __restrict__ bsum)
{
    __shared__ int wsum[16];
    const int tid = threadIdx.x, lane = tid & 63, wid = tid >> 6;
    int n = blockIdx.x * 1024 + tid;
    int v = (n < NODES) ? deg[n] : 0;
    int incl = v;
    #pragma unroll
    for (int off = 1; off < 64; off <<= 1) {
        int t = __shfl_up(incl, off, 64);
        if (lane >= off) incl += t;
    }
    if (lane == 63) wsum[wid] = incl;
    __syncthreads();
    if (tid < 16) {
        int t = wsum[tid];
        #pragma unroll
        for (int off = 1; off < 16; off <<= 1) {
            int u = __shfl_up(t, off, 64);
            if (tid >= off) t += u;
        }
        wsum[tid] = t;
    }
    __syncthreads();
    int wbase = (wid == 0) ? 0 : wsum[wid - 1];
    if (n < NODES) part[n] = wbase + incl - v;
    if (tid == 0) bsum[blockIdx.x] = wsum[15];
}

__global__ __launch_bounds__(64) void k_scan2(const int* __restrict__ bsum, int* __restrict__ bcarry)
{
    int t = threadIdx.x;
    int v = (t < SCAN_BLOCKS) ? bsum[t] : 0;
    int incl = v;
    #pragma unroll
    for (int off = 1; off < 64; off <<= 1) {
        int u = __shfl_up(incl, off, 64);
        if (t >= off) incl += u;
    }
    if (t < SCAN_BLOCKS) bcarry[t] = incl - v;
}

__global__ __launch_bounds__(256) void k_scan3(const int* __restrict__ part,
                                               const int* __restrict__ bcarry,
                                               int* __restrict__ rowptr, int* __restrict__ cursor)
{
    int n = blockIdx.x * 256 + threadIdx.x;
    if (n < NODES) {
        int r = part[n] + bcarry[n >> 10];
        rowptr[n] = r; cursor[n] = r;
    }
    if (n == 0) rowptr[NODES] = EDGES;
}

__global__ __launch_bounds__(256) void k_fill(const int* __restrict__ ei,
                                              int* __restrict__ cursor,
                                              unsigned short* __restrict__ csr)
{
    int e = blockIdx.x * 256 + threadIdx.x;
    if (e < EDGES) {
        int src = __builtin_nontemporal_load(ei + e);
        int dst = __builtin_nontemporal_load(ei + EDGES + e);
        int slot = atomicAdd(&cursor[dst], 1);
        csr[slot] = (unsigned short)src;
    }
}

// ---------------------------------------------------------------------------
// Streaming update + next-message: 32 nodes/block, single reused weight buf.
// ---------------------------------------------------------------------------
__global__ __launch_bounds__(256) void k_upd_msg(
    const float* __restrict__ updW, const float* __restrict__ updb,
    const float* __restrict__ msgW, const float* __restrict__ msgb,
    const bfraw* __restrict__ aggH0, const bfraw* __restrict__ aggH1,
    float* __restrict__ state, bfraw* __restrict__ msg0, bfraw* __restrict__ msg1)
{
    __shared__ float sW[64 * STATE];   // 16 KB, reused
    __shared__ float sUpdb[STATE], sMsgb[STATE];
    __shared__ float sa[32 * 68], ss[32 * 68];

    const int row = threadIdx.x >> 3;
    const int q8  = (threadIdx.x & 7) << 3;
    const int base = blockIdx.x * 32;
    const int n = base + row;

    if (threadIdx.x < STATE) {
        sUpdb[threadIdx.x] = updb[threadIdx.x];
        sMsgb[threadIdx.x] = msgb[threadIdx.x];
    }
    for (int i = threadIdx.x; i < 1024; i += 256)
        *(float4*)(sW + i * 4) = *(const float4*)(updW + i * 4);
    {
        float tmp[8] = {0.f,0.f,0.f,0.f,0.f,0.f,0.f,0.f};
        if (n < NODES) {
            const bfraw* src = (q8 < HALF) ? (aggH0 + (long)n * HALF + q8)
                                           : (aggH1 + (long)n * HALF + (q8 - HALF));
            unpack8(tmp, *(const int4*)src);
        }
        *(float4*)(sa + row * 68 + q8)     = make_float4(tmp[0], tmp[1], tmp[2], tmp[3]);
        *(float4*)(sa + row * 68 + q8 + 4) = make_float4(tmp[4], tmp[5], tmp[6], tmp[7]);
    }
    __syncthreads();

    float a[8];
    #pragma unroll
    for (int j = 0; j < 8; j++) a[j] = sUpdb[q8 + j];
    const float* ar = sa + row * 68;
    #pragma unroll 8
    for (int k = 0; k < STATE; k++) {
        float av = ar[k];
        float4 w0 = *(const float4*)(sW + k * STATE + q8);
        float4 w1 = *(const float4*)(sW + k * STATE + q8 + 4);
        a[0] += av * w0.x; a[1] += av * w0.y; a[2] += av * w0.z; a[3] += av * w0.w;
        a[4] += av * w1.x; a[5] += av * w1.y; a[6] += av * w1.z; a[7] += av * w1.w;
    }
    #pragma unroll
    for (int j = 0; j < 8; j++) a[j] = fmaxf(a[j], 0.f);
    float s[8] = {0.f,0.f,0.f,0.f,0.f,0.f,0.f,0.f};
    if (n < NODES) {
        float4 st0 = *(const float4*)(state + (long)n * STATE + q8);
        float4 st1 = *(const float4*)(state + (long)n * STATE + q8 + 4);
        s[0] = st0.x + a[0]; s[1] = st0.y + a[1]; s[2] = st0.z + a[2]; s[3] = st0.w + a[3];
        s[4] = st1.x + a[4]; s[5] = st1.y + a[5]; s[6] = st1.z + a[6]; s[7] = st1.w + a[7];
        *(float4*)(state + (long)n * STATE + q8)     = make_float4(s[0], s[1], s[2], s[3]);
        *(float4*)(state + (long)n * STATE + q8 + 4) = make_float4(s[4], s[5], s[6], s[7]);
    }
    *(float4*)(ss + row * 68 + q8)     = make_float4(s[0], s[1], s[2], s[3]);
    *(float4*)(ss + row * 68 + q8 + 4) = make_float4(s[4], s[5], s[6], s[7]);
    __syncthreads();
    for (int i = threadIdx.x; i < 1024; i += 256)
        *(float4*)(sW + i * 4) = *(const float4*)(msgW + i * 4);
    __syncthreads();

    float m[8];
    #pragma unroll
    for (int j = 0; j < 8; j++) m[j] = sMsgb[q8 + j];
    const float* sr = ss + row * 68;
    #pragma unroll 8
    for (int k = 0; k < STATE; k++) {
        float sv = sr[k];
        float4 w0 = *(const float4*)(sW + k * STATE + q8);
        float4 w1 = *(const float4*)(sW + k * STATE + q8 + 4);
        m[0] += sv * w0.x; m[1] += sv * w0.y; m[2] += sv * w0.z; m[3] += sv * w0.w;
        m[4] += sv * w1.x; m[5] += sv * w1.y; m[6] += sv * w1.z; m[7] += sv * w1.w;
    }
    #pragma unroll
    for (int j = 0; j < 8; j++) m[j] = fmaxf(m[j], 0.f);
    if (n < NODES) {
        bfraw* dst = (q8 < HALF) ? (msg0 + (long)n * HALF + q8) : (msg1 + (long)n * HALF + (q8 - HALF));
        *(int4*)dst = pack8(m);
    }
}

// ---------------------------------------------------------------------------
// Last round: update + pooling, 32 nodes/block, run-length over sorted batch.
// ---------------------------------------------------------------------------
__global__ __launch_bounds__(256) void k_upd_pool(
    const float* __restrict__ updW, const float* __restrict__ updb,
    const bfraw* __restrict__ aggH0, const bfraw* __restrict__ aggH1,
    const float* __restrict__ state, const int* __restrict__ batch,
    float* __restrict__ gs)
{
    __shared__ float sW[64 * STATE];
    __shared__ float sUpdb[STATE];
    __shared__ float sa[32 * 68];
    __shared__ float ssum[32 * 68];
    __shared__ int   sg[32];

    const int row = threadIdx.x >> 3;
    const int q8  = (threadIdx.x & 7) << 3;
    const int base = blockIdx.x * 32;
    const int n = base + row;

    if (threadIdx.x < STATE) sUpdb[threadIdx.x] = updb[threadIdx.x];
    for (int i = threadIdx.x; i < 1024; i += 256)
        *(float4*)(sW + i * 4) = *(const float4*)(updW + i * 4);
    {
        float tmp[8] = {0.f,0.f,0.f,0.f,0.f,0.f,0.f,0.f};
        if (n < NODES) {
            const bfraw* src = (q8 < HALF) ? (aggH0 + (long)n * HALF + q8)
                                           : (aggH1 + (long)n * HALF + (q8 - HALF));
            unpack8(tmp, *(const int4*)src);
        }
        *(float4*)(sa + row * 68 + q8)     = make_float4(tmp[0], tmp[1], tmp[2], tmp[3]);
        *(float4*)(sa + row * 68 + q8 + 4) = make_float4(tmp[4], tmp[5], tmp[6], tmp[7]);
    }
    if (threadIdx.x < 32) {
        int nn = base + threadIdx.x;
        sg[threadIdx.x] = batch[nn < NODES ? nn : NODES - 1];
    }
    __syncthreads();

    float a[8];
    #pragma unroll
    for (int j = 0; j < 8; j++) a[j] = sUpdb[q8 + j];
    const float* ar = sa + row * 68;
    #pragma unroll 8
    for (int k = 0; k < STATE; k++) {
        float av = ar[k];
        float4 w0 = *(const float4*)(sW + k * STATE + q8);
        float4 w1 = *(const float4*)(sW + k * STATE + q8 + 4);
        a[0] += av * w0.x; a[1] += av * w0.y; a[2] += av * w0.z; a[3] += av * w0.w;
        a[4] += av * w1.x; a[5] += av * w1.y; a[6] += av * w1.z; a[7] += av * w1.w;
    }
    float s[8] = {0.f,0.f,0.f,0.f,0.f,0.f,0.f,0.f};
    if (n < NODES) {
        float4 st0 = *(const float4*)(state + (long)n * STATE + q8);
        float4 st1 = *(const float4*)(state + (long)n * STATE + q8 + 4);
        s[0] = st0.x + fmaxf(a[0], 0.f); s[1] = st0.y + fmaxf(a[1], 0.f);
        s[2] = st0.z + fmaxf(a[2], 0.f); s[3] = st0.w + fmaxf(a[3], 0.f);
        s[4] = st1.x + fmaxf(a[4], 0.f); s[5] = st1.y + fmaxf(a[5], 0.f);
        s[6] = st1.z + fmaxf(a[6], 0.f); s[7] = st1.w + fmaxf(a[7], 0.f);
    }
    *(float4*)(ssum + row * 68 + q8)     = make_float4(s[0], s[1], s[2], s[3]);
    *(float4*)(ssum + row * 68 + q8 + 4) = make_float4(s[4], s[5], s[6], s[7]);
    __syncthreads();

    if (threadIdx.x < STATE) {
        const int f = threadIdx.x;
        float run = ssum[f];
        int g = sg[0];
        #pragma unroll
        for (int r = 1; r < 32; r++) {
            int g2 = sg[r];
            float v = ssum[r * 68 + f];
            if (g2 != g) {
                atomicAdd(&gs[g * STATE + f], run);
                run = v; g = g2;
            } else {
                run += v;
            }
        }
        atomicAdd(&gs[g * STATE + f], run);
    }
}

// ---------------------------------------------------------------------------
// mean = gs@meanW+b ; std = exp(0.5*clip(gs@lvW+b, -20, 2)) -> out[2,256,32]
// ---------------------------------------------------------------------------
__global__ __launch_bounds__(64) void k_final(
    const float* __restrict__ gs,
    const float* __restrict__ meanW, const float* __restrict__ meanb,
    const float* __restrict__ lvW, const float* __restrict__ lvb,
    float* __restrict__ out)
{
    __shared__ float row[STATE];
    const int g = blockIdx.x;
    const int j = threadIdx.x;
    row[j] = gs[g * STATE + j];
    __syncthreads();
    if (j < M_OUT) {
        float acc = meanb[j];
        #pragma unroll
        for (int k = 0; k < STATE; k++) acc += row[k] * meanW[k * M_OUT + j];
        out[g * M_OUT + j] = acc;
    } else {
        int jj = j - M_OUT;
        float acc = lvb[jj];
        #pragma unroll
        for (int k = 0; k < STATE; k++) acc += row[k] * lvW[k * M_OUT + jj];
        acc = fminf(fmaxf(acc, -20.f), 2.f);
        out[GRAPHS * M_OUT + g * M_OUT + jj] = expf(0.5f * acc);
    }
}

extern "C" void kernel_launch(void* const* d_in, const int* in_sizes, int n_in,
                              void* d_out, int out_size, void* d_ws, size_t ws_size,
                              hipStream_t stream) {
    const float* x     = (const float*)d_in[0];
    const int*   ei    = (const int*)d_in[1];   // [2, E]: row0 = src (gather), row1 = dst (scatter)
    const int*   batch = (const int*)d_in[2];
    const float* inW   = (const float*)d_in[3];
    const float* inb   = (const float*)d_in[4];
    const float* msgW  = (const float*)d_in[5]; // [4,64,64]
    const float* msgb  = (const float*)d_in[6]; // [4,64]
    const float* updW  = (const float*)d_in[7];
    const float* updb  = (const float*)d_in[8];
    const float* meanW = (const float*)d_in[9];
    const float* meanb = (const float*)d_in[10];
    const float* lvW   = (const float*)d_in[11];
    const float* lvb   = (const float*)d_in[12];
    float* out = (float*)d_out;

    const size_t NS   = (size_t)NODES * STATE * sizeof(float);
    const size_t PLB  = (size_t)PLANE * sizeof(bfraw);
    const size_t AGH  = (size_t)NODES * HALF * sizeof(bfraw);
    char* ws = (char*)d_ws;
    size_t off = 0;
    auto alloc = [&](size_t bytes) { void* p = ws + off; off += (bytes + 255) & ~(size_t)255; return p; };
    float* state  = (float*)alloc(NS);
    bfraw* msgA0  = (bfraw*)alloc(PLB);
    bfraw* msgA1  = (bfraw*)alloc(PLB);
    bfraw* msgB0  = (bfraw*)alloc(PLB);
    bfraw* msgB1  = (bfraw*)alloc(PLB);
    bfraw* aggH0  = (bfraw*)alloc(AGH);
    bfraw* aggH1  = (bfraw*)alloc(AGH);
    float* gs     = (float*)alloc((size_t)GRAPHS * STATE * sizeof(float));
    int*   deg    = (int*)alloc((size_t)NODES * sizeof(int));
    int*   part   = (int*)alloc((size_t)NODES * sizeof(int));
    int*   bsum   = (int*)alloc((size_t)SCAN_BLOCKS * sizeof(int));
    int*   bcarry = (int*)alloc((size_t)SCAN_BLOCKS * sizeof(int));
    int*   rowptr = (int*)alloc((size_t)(NODES + 1) * sizeof(int));
    int*   cursor = (int*)alloc((size_t)NODES * sizeof(int));
    unsigned short* csr = (unsigned short*)alloc((size_t)EDGES * sizeof(unsigned short));

    hipMemsetAsync(deg, 0, (size_t)NODES * sizeof(int), stream);
    hipMemsetAsync(gs, 0, (size_t)GRAPHS * STATE * sizeof(float), stream);

    k_hist<<<(EDGES + 255) / 256, 256, 0, stream>>>(ei, deg);
    k_scan1<<<SCAN_BLOCKS, 1024, 0, stream>>>(deg, part, bsum);
    k_scan2<<<1, 64, 0, stream>>>(bsum, bcarry);
    k_scan3<<<(NODES + 255) / 256, 256, 0, stream>>>(part, bcarry, rowptr, cursor);
    k_fill<<<(EDGES + 255) / 256, 256, 0, stream>>>(ei, cursor, csr);

    k_in_msg<<<NT32, 256, 0, stream>>>(x, inW, inb, msgW, msgb, state, msgA0, msgA1);

    bfraw *mi0 = msgA0, *mi1 = msgA1, *mo0 = msgB0, *mo1 = msgB1;
    for (int r = 0; r < ROUNDS; r++) {
        k_gather<<<NT32, 256, 0, stream>>>(rowptr, csr, mi0, mi1, aggH0, aggH1);
        if (r < ROUNDS - 1) {
            k_upd_msg<<<NT32, 256, 0, stream>>>(
                updW + r * STATE * STATE, updb + r * STATE,
                msgW + (r + 1) * STATE * STATE, msgb + (r + 1) * STATE,
                aggH0, aggH1, state, mo0, mo1);
            bfraw* t0 = mi0; mi0 = mo0; mo0 = t0;
            bfraw* t1 = mi1; mi1 = mo1; mo1 = t1;
        } else {
            k_upd_pool<<<NT32, 256, 0, stream>>>(
                updW + r * STATE * STATE, updb + r * STATE,
                aggH0, aggH1, state, batch, gs);
        }
    }

    k_final<<<GRAPHS, 64, 0, stream>>>(gs, meanW, meanb, lvW, lvb, out);
}

// Round 16
// 374.487 us; speedup vs baseline: 1.0168x; 1.0168x over previous
//
#include <hip/hip_runtime.h>
#include <math.h>

#define NODES  50000
#define EDGES  800000
#define GRAPHS 256
#define FEAT   128
#define STATE  64
#define M_OUT  32
#define ROUNDS 4
#define NT32   ((NODES + 31) / 32)     // 1563 tiles of 32 nodes
#define HALF   32                      // features per plane
#define PLANE  (50000L * 32L)          // bf16 elements per plane (3.2 MB)
#define SCAN_BLOCKS ((NODES + 1023) / 1024)  // 49

typedef unsigned short bfraw;

__device__ __forceinline__ float bf2f(bfraw u) {
    union { unsigned int i; float f; } v; v.i = ((unsigned int)u) << 16; return v.f;
}
__device__ __forceinline__ bfraw f2bf(float f) {
    union { float f; unsigned int i; } v; v.f = f;
    unsigned int r = v.i + 0x7FFF + ((v.i >> 16) & 1); // round-nearest-even
    return (bfraw)(r >> 16);
}
__device__ __forceinline__ int packbf(float lo, float hi) {
    return ((int)f2bf(hi) << 16) | (int)f2bf(lo);
}
__device__ __forceinline__ void addv8(float* acc, int4 v, float m) {
    union { int i; float f; } t;
    t.i = v.x << 16;                  acc[0] += t.f * m;
    t.i = v.x & (int)0xffff0000;      acc[1] += t.f * m;
    t.i = v.y << 16;                  acc[2] += t.f * m;
    t.i = v.y & (int)0xffff0000;      acc[3] += t.f * m;
    t.i = v.z << 16;                  acc[4] += t.f * m;
    t.i = v.z & (int)0xffff0000;      acc[5] += t.f * m;
    t.i = v.w << 16;                  acc[6] += t.f * m;
    t.i = v.w & (int)0xffff0000;      acc[7] += t.f * m;
}
__device__ __forceinline__ void unpack8(float* d, int4 v) {
    union { int i; float f; } t;
    t.i = v.x << 16;              d[0] = t.f;
    t.i = v.x & (int)0xffff0000;  d[1] = t.f;
    t.i = v.y << 16;              d[2] = t.f;
    t.i = v.y & (int)0xffff0000;  d[3] = t.f;
    t.i = v.z << 16;              d[4] = t.f;
    t.i = v.z & (int)0xffff0000;  d[5] = t.f;
    t.i = v.w << 16;              d[6] = t.f;
    t.i = v.w & (int)0xffff0000;  d[7] = t.f;
}
__device__ __forceinline__ int4 pack8(const float* a) {
    int4 o;
    o.x = packbf(a[0], a[1]); o.y = packbf(a[2], a[3]);
    o.z = packbf(a[4], a[5]); o.w = packbf(a[6], a[7]);
    return o;
}

// ---------------------------------------------------------------------------
// Merged full-row gather: 8 lanes/node (lanes 0-3 plane0, 4-7 plane1),
// 32 nodes/block, 16B loads, 8 edges in flight (measured best depth).
// uint16 csr, bf16 agg output.
// ---------------------------------------------------------------------------
__global__ __launch_bounds__(256) void k_gather(
    const int* __restrict__ rowptr, const unsigned short* __restrict__ csr,
    const bfraw* __restrict__ plane0, const bfraw* __restrict__ plane1,
    bfraw* __restrict__ aggH0, bfraw* __restrict__ aggH1)
{
    // pre-warm: stream a sequential slice of each plane into cache
    float dummy = 0.f;
    {
        const bfraw* p = (threadIdx.x < 128) ? plane0 : plane1;
        long s = (long)blockIdx.x * 1024 + (long)(threadIdx.x & 127) * 8;
        if (s + 8 <= PLANE) {
            int4 a = *(const int4*)(p + s);
            union { int i; float f; } t; t.i = a.x << 16;
            dummy = t.f;   // finite; folded below with *0.0f
        }
    }

    int n = blockIdx.x * 32 + (threadIdx.x >> 3);
    if (n >= NODES) return;
    const int q = (threadIdx.x & 7) * 8;            // 0..56
    const bfraw* plane = (q < HALF) ? plane0 : plane1;
    const int qq = (q < HALF) ? q : q - HALF;       // offset within plane row
    int beg = rowptr[n], end = rowptr[n + 1];

    float acc[8] = {0.f, 0.f, 0.f, 0.f, 0.f, 0.f, 0.f, 0.f};
    for (int i = beg; i < end; i += 8) {
        int last = end - 1;
        int i1 = i + 1 < last ? i + 1 : last;
        int i2 = i + 2 < last ? i + 2 : last;
        int i3 = i + 3 < last ? i + 3 : last;
        int i4 = i + 4 < last ? i + 4 : last;
        int i5 = i + 5 < last ? i + 5 : last;
        int i6 = i + 6 < last ? i + 6 : last;
        int i7 = i + 7 < last ? i + 7 : last;
        int s0 = csr[i],  s1 = csr[i1], s2 = csr[i2], s3 = csr[i3];
        int s4 = csr[i4], s5 = csr[i5], s6 = csr[i6], s7 = csr[i7];
        int4 v0 = *(const int4*)(plane + (long)s0 * HALF + qq);
        int4 v1 = *(const int4*)(plane + (long)s1 * HALF + qq);
        int4 v2 = *(const int4*)(plane + (long)s2 * HALF + qq);
        int4 v3 = *(const int4*)(plane + (long)s3 * HALF + qq);
        int4 v4 = *(const int4*)(plane + (long)s4 * HALF + qq);
        int4 v5 = *(const int4*)(plane + (long)s5 * HALF + qq);
        int4 v6 = *(const int4*)(plane + (long)s6 * HALF + qq);
        int4 v7 = *(const int4*)(plane + (long)s7 * HALF + qq);
        float m1 = (i + 1 < end) ? 1.f : 0.f;
        float m2 = (i + 2 < end) ? 1.f : 0.f;
        float m3 = (i + 3 < end) ? 1.f : 0.f;
        float m4 = (i + 4 < end) ? 1.f : 0.f;
        float m5 = (i + 5 < end) ? 1.f : 0.f;
        float m6 = (i + 6 < end) ? 1.f : 0.f;
        float m7 = (i + 7 < end) ? 1.f : 0.f;
        addv8(acc, v0, 1.f); addv8(acc, v1, m1);
        addv8(acc, v2, m2);  addv8(acc, v3, m3);
        addv8(acc, v4, m4);  addv8(acc, v5, m5);
        addv8(acc, v6, m6);  addv8(acc, v7, m7);
    }
    acc[0] += dummy * 0.0f;

    bfraw* aout = (q < HALF) ? (aggH0 + (long)n * HALF + qq) : (aggH1 + (long)n * HALF + qq);
    *(int4*)aout = pack8(acc);
}

// ---------------------------------------------------------------------------
// state = relu(x @ inW + inb); msg planes = relu(state @ msgW + msgb).
// 32 nodes/block, 8 thr/node x 8 feats; one reused 16KB weight buffer.
// ---------------------------------------------------------------------------
__global__ __launch_bounds__(256) void k_in_msg(
    const float* __restrict__ x, const float* __restrict__ inW, const float* __restrict__ inb,
    const float* __restrict__ msgW, const float* __restrict__ msgb,
    float* __restrict__ state, bfraw* __restrict__ msg0, bfraw* __restrict__ msg1)
{
    __shared__ float sW[64 * STATE];        // 16 KB, reused 3x
    __shared__ float sInb[STATE], sMsgb[STATE];
    __shared__ float sx[32 * 132];          // 16.9 KB
    __shared__ float ss[32 * 68];           // 8.7 KB

    const int row = threadIdx.x >> 3;           // node in tile
    const int q8  = (threadIdx.x & 7) << 3;     // feature offset (8 wide)
    const int base = blockIdx.x * 32;
    const int n = base + row;

    if (threadIdx.x < STATE) {
        sInb[threadIdx.x]  = inb[threadIdx.x];
        sMsgb[threadIdx.x] = msgb[threadIdx.x];
    }
    for (int i = threadIdx.x; i < 1024; i += 256) {
        int r = i >> 5, q = (i & 31) << 2;
        float4 v = make_float4(0.f, 0.f, 0.f, 0.f);
        if (base + r < NODES) v = *(const float4*)(x + (long)(base + r) * FEAT + q);
        *(float4*)(sx + r * 132 + q) = v;
    }
    for (int i = threadIdx.x; i < 1024; i += 256)
        *(float4*)(sW + i * 4) = *(const float4*)(inW + i * 4);
    __syncthreads();

    float a[8];
    #pragma unroll
    for (int j = 0; j < 8; j++) a[j] = sInb[q8 + j];
    const float* xr = sx + row * 132;
    #pragma unroll 8
    for (int k = 0; k < 64; k++) {
        float xv = xr[k];
        float4 w0 = *(const float4*)(sW + k * STATE + q8);
        float4 w1 = *(const float4*)(sW + k * STATE + q8 + 4);
        a[0] += xv * w0.x; a[1] += xv * w0.y; a[2] += xv * w0.z; a[3] += xv * w0.w;
        a[4] += xv * w1.x; a[5] += xv * w1.y; a[6] += xv * w1.z; a[7] += xv * w1.w;
    }
    __syncthreads();
    for (int i = threadIdx.x; i < 1024; i += 256)
        *(float4*)(sW + i * 4) = *(const float4*)(inW + 64 * STATE + i * 4);
    __syncthreads();
    #pragma unroll 8
    for (int k = 0; k < 64; k++) {
        float xv = xr[64 + k];
        float4 w0 = *(const float4*)(sW + k * STATE + q8);
        float4 w1 = *(const float4*)(sW + k * STATE + q8 + 4);
        a[0] += xv * w0.x; a[1] += xv * w0.y; a[2] += xv * w0.z; a[3] += xv * w0.w;
        a[4] += xv * w1.x; a[5] += xv * w1.y; a[6] += xv * w1.z; a[7] += xv * w1.w;
    }
    #pragma unroll
    for (int j = 0; j < 8; j++) a[j] = fmaxf(a[j], 0.f);
    if (n < NODES) {
        *(float4*)(state + (long)n * STATE + q8)     = make_float4(a[0], a[1], a[2], a[3]);
        *(float4*)(state + (long)n * STATE + q8 + 4) = make_float4(a[4], a[5], a[6], a[7]);
    }
    *(float4*)(ss + row * 68 + q8)     = make_float4(a[0], a[1], a[2], a[3]);
    *(float4*)(ss + row * 68 + q8 + 4) = make_float4(a[4], a[5], a[6], a[7]);
    __syncthreads();
    for (int i = threadIdx.x; i < 1024; i += 256)
        *(float4*)(sW + i * 4) = *(const float4*)(msgW + i * 4);
    __syncthreads();

    float m[8];
    #pragma unroll
    for (int j = 0; j < 8; j++) m[j] = sMsgb[q8 + j];
    const float* sr = ss + row * 68;
    #pragma unroll 8
    for (int k = 0; k < STATE; k++) {
        float sv = sr[k];
        float4 w0 = *(const float4*)(sW + k * STATE + q8);
        float4 w1 = *(const float4*)(sW + k * STATE + q8 + 4);
        m[0] += sv * w0.x; m[1] += sv * w0.y; m[2] += sv * w0.z; m[3] += sv * w0.w;
        m[4] += sv * w1.x; m[5] += sv * w1.y; m[6] += sv * w1.z; m[7] += sv * w1.w;
    }
    #pragma unroll
    for (int j = 0; j < 8; j++) m[j] = fmaxf(m[j], 0.f);
    if (n < NODES) {
        bfraw* dst = (q8 < HALF) ? (msg0 + (long)n * HALF + q8) : (msg1 + (long)n * HALF + (q8 - HALF));
        *(int4*)dst = pack8(m);
    }
}

// ---------------------------------------------------------------------------
// CSR build: histogram + hierarchical scan + fill (u16 csr, NT edge streams)
// ---------------------------------------------------------------------------
__global__ __launch_bounds__(256) void k_hist(const int* __restrict__ ei, int* __restrict__ deg)
{
    int e = blockIdx.x * 256 + threadIdx.x;
    if (e < EDGES) atomicAdd(&deg[__builtin_nontemporal_load(ei + EDGES + e)], 1);
}

__global__ __launch_bounds__(1024) void k_scan1(const int* __restrict__ deg,
                                                int* __restrict__ part, int* __restrict__ bsum)
{
    __shared__ int wsum[16];
    const int tid = threadIdx.x, lane = tid & 63, wid = tid >> 6;
    int n = blockIdx.x * 1024 + tid;
    int v = (n < NODES) ? deg[n] : 0;
    int incl = v;
    #pragma unroll
    for (int off = 1; off < 64; off <<= 1) {
        int t = __shfl_up(incl, off, 64);
        if (lane >= off) incl += t;
    }
    if (lane == 63) wsum[wid] = incl;
    __syncthreads();
    if (tid < 16) {
        int t = wsum[tid];
        #pragma unroll
        for (int off = 1; off < 16; off <<= 1) {
            int u = __shfl_up(t, off, 64);
            if (tid >= off) t += u;
        }
        wsum[tid] = t;
    }
    __syncthreads();
    int wbase = (wid == 0) ? 0 : wsum[wid - 1];
    if (n < NODES) part[n] = wbase + incl - v;
    if (tid == 0) bsum[blockIdx.x] = wsum[15];
}

__global__ __launch_bounds__(64) void k_scan2(const int* __restrict__ bsum, int* __restrict__ bcarry)
{
    int t = threadIdx.x;
    int v = (t < SCAN_BLOCKS) ? bsum[t] : 0;
    int incl = v;
    #pragma unroll
    for (int off = 1; off < 64; off <<= 1) {
        int u = __shfl_up(incl, off, 64);
        if (t >= off) incl += u;
    }
    if (t < SCAN_BLOCKS) bcarry[t] = incl - v;
}

__global__ __launch_bounds__(256) void k_scan3(const int* __restrict__ part,
                                               const int* __restrict__ bcarry,
                                               int* __restrict__ rowptr, int* __restrict__ cursor)
{
    int n = blockIdx.x * 256 + threadIdx.x;
    if (n < NODES) {
        int r = part[n] + bcarry[n >> 10];
        rowptr[n] = r; cursor[n] = r;
    }
    if (n == 0) rowptr[NODES] = EDGES;
}

__global__ __launch_bounds__(256) void k_fill(const int* __restrict__ ei,
                                              int* __restrict__ cursor,
                                              unsigned short* __restrict__ csr)
{
    int e = blockIdx.x * 256 + threadIdx.x;
    if (e < EDGES) {
        int src = __builtin_nontemporal_load(ei + e);
        int dst = __builtin_nontemporal_load(ei + EDGES + e);
        int slot = atomicAdd(&cursor[dst], 1);
        csr[slot] = (unsigned short)src;
    }
}

// ---------------------------------------------------------------------------
// Streaming update + next-message: 32 nodes/block, single reused weight buf.
// ---------------------------------------------------------------------------
__global__ __launch_bounds__(256) void k_upd_msg(
    const float* __restrict__ updW, const float* __restrict__ updb,
    const float* __restrict__ msgW, const float* __restrict__ msgb,
    const bfraw* __restrict__ aggH0, const bfraw* __restrict__ aggH1,
    float* __restrict__ state, bfraw* __restrict__ msg0, bfraw* __restrict__ msg1)
{
    __shared__ float sW[64 * STATE];   // 16 KB, reused
    __shared__ float sUpdb[STATE], sMsgb[STATE];
    __shared__ float sa[32 * 68], ss[32 * 68];

    const int row = threadIdx.x >> 3;
    const int q8  = (threadIdx.x & 7) << 3;
    const int base = blockIdx.x * 32;
    const int n = base + row;

    if (threadIdx.x < STATE) {
        sUpdb[threadIdx.x] = updb[threadIdx.x];
        sMsgb[threadIdx.x] = msgb[threadIdx.x];
    }
    for (int i = threadIdx.x; i < 1024; i += 256)
        *(float4*)(sW + i * 4) = *(const float4*)(updW + i * 4);
    {
        float tmp[8] = {0.f,0.f,0.f,0.f,0.f,0.f,0.f,0.f};
        if (n < NODES) {
            const bfraw* src = (q8 < HALF) ? (aggH0 + (long)n * HALF + q8)
                                           : (aggH1 + (long)n * HALF + (q8 - HALF));
            unpack8(tmp, *(const int4*)src);
        }
        *(float4*)(sa + row * 68 + q8)     = make_float4(tmp[0], tmp[1], tmp[2], tmp[3]);
        *(float4*)(sa + row * 68 + q8 + 4) = make_float4(tmp[4], tmp[5], tmp[6], tmp[7]);
    }
    __syncthreads();

    float a[8];
    #pragma unroll
    for (int j = 0; j < 8; j++) a[j] = sUpdb[q8 + j];
    const float* ar = sa + row * 68;
    #pragma unroll 8
    for (int k = 0; k < STATE; k++) {
        float av = ar[k];
        float4 w0 = *(const float4*)(sW + k * STATE + q8);
        float4 w1 = *(const float4*)(sW + k * STATE + q8 + 4);
        a[0] += av * w0.x; a[1] += av * w0.y; a[2] += av * w0.z; a[3] += av * w0.w;
        a[4] += av * w1.x; a[5] += av * w1.y; a[6] += av * w1.z; a[7] += av * w1.w;
    }
    #pragma unroll
    for (int j = 0; j < 8; j++) a[j] = fmaxf(a[j], 0.f);
    float s[8] = {0.f,0.f,0.f,0.f,0.f,0.f,0.f,0.f};
    if (n < NODES) {
        float4 st0 = *(const float4*)(state + (long)n * STATE + q8);
        float4 st1 = *(const float4*)(state + (long)n * STATE + q8 + 4);
        s[0] = st0.x + a[0]; s[1] = st0.y + a[1]; s[2] = st0.z + a[2]; s[3] = st0.w + a[3];
        s[4] = st1.x + a[4]; s[5] = st1.y + a[5]; s[6] = st1.z + a[6]; s[7] = st1.w + a[7];
        *(float4*)(state + (long)n * STATE + q8)     = make_float4(s[0], s[1], s[2], s[3]);
        *(float4*)(state + (long)n * STATE + q8 + 4) = make_float4(s[4], s[5], s[6], s[7]);
    }
    *(float4*)(ss + row * 68 + q8)     = make_float4(s[0], s[1], s[2], s[3]);
    *(float4*)(ss + row * 68 + q8 + 4) = make_float4(s[4], s[5], s[6], s[7]);
    __syncthreads();
    for (int i = threadIdx.x; i < 1024; i += 256)
        *(float4*)(sW + i * 4) = *(const float4*)(msgW + i * 4);
    __syncthreads();

    float m[8];
    #pragma unroll
    for (int j = 0; j < 8; j++) m[j] = sMsgb[q8 + j];
    const float* sr = ss + row * 68;
    #pragma unroll 8
    for (int k = 0; k < STATE; k++) {
        float sv = sr[k];
        float4 w0 = *(const float4*)(sW + k * STATE + q8);
        float4 w1 = *(const float4*)(sW + k * STATE + q8 + 4);
        m[0] += sv * w0.x; m[1] += sv * w0.y; m[2] += sv * w0.z; m[3] += sv * w0.w;
        m[4] += sv * w1.x; m[5] += sv * w1.y; m[6] += sv * w1.z; m[7] += sv * w1.w;
    }
    #pragma unroll
    for (int j = 0; j < 8; j++) m[j] = fmaxf(m[j], 0.f);
    if (n < NODES) {
        bfraw* dst = (q8 < HALF) ? (msg0 + (long)n * HALF + q8) : (msg1 + (long)n * HALF + (q8 - HALF));
        *(int4*)dst = pack8(m);
    }
}

// ---------------------------------------------------------------------------
// Last round: update + pooling, 32 nodes/block, run-length over sorted batch.
// ---------------------------------------------------------------------------
__global__ __launch_bounds__(256) void k_upd_pool(
    const float* __restrict__ updW, const float* __restrict__ updb,
    const bfraw* __restrict__ aggH0, const bfraw* __restrict__ aggH1,
    const float* __restrict__ state, const int* __restrict__ batch,
    float* __restrict__ gs)
{
    __shared__ float sW[64 * STATE];
    __shared__ float sUpdb[STATE];
    __shared__ float sa[32 * 68];
    __shared__ float ssum[32 * 68];
    __shared__ int   sg[32];

    const int row = threadIdx.x >> 3;
    const int q8  = (threadIdx.x & 7) << 3;
    const int base = blockIdx.x * 32;
    const int n = base + row;

    if (threadIdx.x < STATE) sUpdb[threadIdx.x] = updb[threadIdx.x];
    for (int i = threadIdx.x; i < 1024; i += 256)
        *(float4*)(sW + i * 4) = *(const float4*)(updW + i * 4);
    {
        float tmp[8] = {0.f,0.f,0.f,0.f,0.f,0.f,0.f,0.f};
        if (n < NODES) {
            const bfraw* src = (q8 < HALF) ? (aggH0 + (long)n * HALF + q8)
                                           : (aggH1 + (long)n * HALF + (q8 - HALF));
            unpack8(tmp, *(const int4*)src);
        }
        *(float4*)(sa + row * 68 + q8)     = make_float4(tmp[0], tmp[1], tmp[2], tmp[3]);
        *(float4*)(sa + row * 68 + q8 + 4) = make_float4(tmp[4], tmp[5], tmp[6], tmp[7]);
    }
    if (threadIdx.x < 32) {
        int nn = base + threadIdx.x;
        sg[threadIdx.x] = batch[nn < NODES ? nn : NODES - 1];
    }
    __syncthreads();

    float a[8];
    #pragma unroll
    for (int j = 0; j < 8; j++) a[j] = sUpdb[q8 + j];
    const float* ar = sa + row * 68;
    #pragma unroll 8
    for (int k = 0; k < STATE; k++) {
        float av = ar[k];
        float4 w0 = *(const float4*)(sW + k * STATE + q8);
        float4 w1 = *(const float4*)(sW + k * STATE + q8 + 4);
        a[0] += av * w0.x; a[1] += av * w0.y; a[2] += av * w0.z; a[3] += av * w0.w;
        a[4] += av * w1.x; a[5] += av * w1.y; a[6] += av * w1.z; a[7] += av * w1.w;
    }
    float s[8] = {0.f,0.f,0.f,0.f,0.f,0.f,0.f,0.f};
    if (n < NODES) {
        float4 st0 = *(const float4*)(state + (long)n * STATE + q8);
        float4 st1 = *(const float4*)(state + (long)n * STATE + q8 + 4);
        s[0] = st0.x + fmaxf(a[0], 0.f); s[1] = st0.y + fmaxf(a[1], 0.f);
        s[2] = st0.z + fmaxf(a[2], 0.f); s[3] = st0.w + fmaxf(a[3], 0.f);
        s[4] = st1.x + fmaxf(a[4], 0.f); s[5] = st1.y + fmaxf(a[5], 0.f);
        s[6] = st1.z + fmaxf(a[6], 0.f); s[7] = st1.w + fmaxf(a[7], 0.f);
    }
    *(float4*)(ssum + row * 68 + q8)     = make_float4(s[0], s[1], s[2], s[3]);
    *(float4*)(ssum + row * 68 + q8 + 4) = make_float4(s[4], s[5], s[6], s[7]);
    __syncthreads();

    if (threadIdx.x < STATE) {
        const int f = threadIdx.x;
        float run = ssum[f];
        int g = sg[0];
        #pragma unroll
        for (int r = 1; r < 32; r++) {
            int g2 = sg[r];
            float v = ssum[r * 68 + f];
            if (g2 != g) {
                atomicAdd(&gs[g * STATE + f], run);
                run = v; g = g2;
            } else {
                run += v;
            }
        }
        atomicAdd(&gs[g * STATE + f], run);
    }
}

// ---------------------------------------------------------------------------
// mean = gs@meanW+b ; std = exp(0.5*clip(gs@lvW+b, -20, 2)) -> out[2,256,32]
// ---------------------------------------------------------------------------
__global__ __launch_bounds__(64) void k_final(
    const float* __restrict__ gs,
    const float* __restrict__ meanW, const float* __restrict__ meanb,
    const float* __restrict__ lvW, const float* __restrict__ lvb,
    float* __restrict__ out)
{
    __shared__ float row[STATE];
    const int g = blockIdx.x;
    const int j = threadIdx.x;
    row[j] = gs[g * STATE + j];
    __syncthreads();
    if (j < M_OUT) {
        float acc = meanb[j];
        #pragma unroll
        for (int k = 0; k < STATE; k++) acc += row[k] * meanW[k * M_OUT + j];
        out[g * M_OUT + j] = acc;
    } else {
        int jj = j - M_OUT;
        float acc = lvb[jj];
        #pragma unroll
        for (int k = 0; k < STATE; k++) acc += row[k] * lvW[k * M_OUT + jj];
        acc = fminf(fmaxf(acc, -20.f), 2.f);
        out[GRAPHS * M_OUT + g * M_OUT + jj] = expf(0.5f * acc);
    }
}

extern "C" void kernel_launch(void* const* d_in, const int* in_sizes, int n_in,
                              void* d_out, int out_size, void* d_ws, size_t ws_size,
                              hipStream_t stream) {
    const float* x     = (const float*)d_in[0];
    const int*   ei    = (const int*)d_in[1];   // [2, E]: row0 = src (gather), row1 = dst (scatter)
    const int*   batch = (const int*)d_in[2];
    const float* inW   = (const float*)d_in[3];
    const float* inb   = (const float*)d_in[4];
    const float* msgW  = (const float*)d_in[5]; // [4,64,64]
    const float* msgb  = (const float*)d_in[6]; // [4,64]
    const float* updW  = (const float*)d_in[7];
    const float* updb  = (const float*)d_in[8];
    const float* meanW = (const float*)d_in[9];
    const float* meanb = (const float*)d_in[10];
    const float* lvW   = (const float*)d_in[11];
    const float* lvb   = (const float*)d_in[12];
    float* out = (float*)d_out;

    const size_t NS   = (size_t)NODES * STATE * sizeof(float);
    const size_t PLB  = (size_t)PLANE * sizeof(bfraw);
    const size_t AGH  = (size_t)NODES * HALF * sizeof(bfraw);
    char* ws = (char*)d_ws;
    size_t off = 0;
    auto alloc = [&](size_t bytes) { void* p = ws + off; off += (bytes + 255) & ~(size_t)255; return p; };
    float* state  = (float*)alloc(NS);
    bfraw* msgA0  = (bfraw*)alloc(PLB);
    bfraw* msgA1  = (bfraw*)alloc(PLB);
    bfraw* msgB0  = (bfraw*)alloc(PLB);
    bfraw* msgB1  = (bfraw*)alloc(PLB);
    bfraw* aggH0  = (bfraw*)alloc(AGH);
    bfraw* aggH1  = (bfraw*)alloc(AGH);
    float* gs     = (float*)alloc((size_t)GRAPHS * STATE * sizeof(float));
    int*   deg    = (int*)alloc((size_t)NODES * sizeof(int));
    int*   part   = (int*)alloc((size_t)NODES * sizeof(int));
    int*   bsum   = (int*)alloc((size_t)SCAN_BLOCKS * sizeof(int));
    int*   bcarry = (int*)alloc((size_t)SCAN_BLOCKS * sizeof(int));
    int*   rowptr = (int*)alloc((size_t)(NODES + 1) * sizeof(int));
    int*   cursor = (int*)alloc((size_t)NODES * sizeof(int));
    unsigned short* csr = (unsigned short*)alloc((size_t)EDGES * sizeof(unsigned short));

    hipMemsetAsync(deg, 0, (size_t)NODES * sizeof(int), stream);
    hipMemsetAsync(gs, 0, (size_t)GRAPHS * STATE * sizeof(float), stream);

    k_hist<<<(EDGES + 255) / 256, 256, 0, stream>>>(ei, deg);
    k_scan1<<<SCAN_BLOCKS, 1024, 0, stream>>>(deg, part, bsum);
    k_scan2<<<1, 64, 0, stream>>>(bsum, bcarry);
    k_scan3<<<(NODES + 255) / 256, 256, 0, stream>>>(part, bcarry, rowptr, cursor);
    k_fill<<<(EDGES + 255) / 256, 256, 0, stream>>>(ei, cursor, csr);

    k_in_msg<<<NT32, 256, 0, stream>>>(x, inW, inb, msgW, msgb, state, msgA0, msgA1);

    bfraw *mi0 = msgA0, *mi1 = msgA1, *mo0 = msgB0, *mo1 = msgB1;
    for (int r = 0; r < ROUNDS; r++) {
        k_gather<<<NT32, 256, 0, stream>>>(rowptr, csr, mi0, mi1, aggH0, aggH1);
        if (r < ROUNDS - 1) {
            k_upd_msg<<<NT32, 256, 0, stream>>>(
                updW + r * STATE * STATE, updb + r * STATE,
                msgW + (r + 1) * STATE * STATE, msgb + (r + 1) * STATE,
                aggH0, aggH1, state, mo0, mo1);
            bfraw* t0 = mi0; mi0 = mo0; mo0 = t0;
            bfraw* t1 = mi1; mi1 = mo1; mo1 = t1;
        } else {
            k_upd_pool<<<NT32, 256, 0, stream>>>(
                updW + r * STATE * STATE, updb + r * STATE,
                aggH0, aggH1, state, batch, gs);
        }
    }

    k_final<<<GRAPHS, 64, 0, stream>>>(gs, meanW, meanb, lvW, lvb, out);
}